// Round 6
// baseline (259.215 us; speedup 1.0000x reference)
//
#include <hip/hip_runtime.h>
#include <cstdint>
#include <cstddef>

// Problem constants: W is [COUT, CIN]; x is [4*4096, CIN]. All I/O fp32.
#define CIN  1024
#define COUT 1024

typedef __attribute__((ext_vector_type(8))) short bf16x8;
typedef __attribute__((ext_vector_type(4))) float f32x4;

// ---------- fp32 -> bf16 (round-to-nearest-even) ----------
__device__ __forceinline__ unsigned short f2bf(float f) {
    union { float f; unsigned int i; } v;
    v.f = f;
    unsigned int u = v.i;
    u += 0x7FFFu + ((u >> 16) & 1u);
    return (unsigned short)(u >> 16);
}

// ---------- kernel 1: zero the fp32 W accumulation buffer (1M floats) ----------
__global__ void zero_f32(float4* __restrict__ p) {
    p[blockIdx.x * 256 + threadIdx.x] = float4{0.f, 0.f, 0.f, 0.f};
}

// ---------- kernel 2: scatter-add fp32 COO values into dense fp32 W ----------
__global__ void scatter_add(const float* __restrict__ vals,
                            const int* __restrict__ rows,
                            const int* __restrict__ cols,
                            float* __restrict__ W, int nnz) {
    int i = blockIdx.x * 256 + threadIdx.x;
    if (i < nnz) {
        atomicAdd(W + (size_t)rows[i] * CIN + cols[i], vals[i]);
    }
}

// ---------- kernel 3: fp32 -> bf16 bulk convert (used for W and for x) ----------
// Round-4 lesson: cvt_x is a 2x compression of a multi-shared A-stream, not
// overhead — fusing it into the GEMM doubled L3 traffic (+40us). Keep it.
__global__ void cvt_bf16_bulk(const float* __restrict__ src, unsigned short* __restrict__ dst) {
    size_t i = ((size_t)blockIdx.x * 256 + threadIdx.x) * 8;
    float4 v0 = *(const float4*)(src + i);
    float4 v1 = *(const float4*)(src + i + 4);
    union { bf16x8 v; unsigned short u[8]; } w;
    w.u[0] = f2bf(v0.x); w.u[1] = f2bf(v0.y); w.u[2] = f2bf(v0.z); w.u[3] = f2bf(v0.w);
    w.u[4] = f2bf(v1.x); w.u[5] = f2bf(v1.y); w.u[6] = f2bf(v1.z); w.u[7] = f2bf(v1.w);
    *(bf16x8*)(dst + i) = w.v;
}

// ---------- kernel 4: 256x128-tile GEMM, BK=32, 48 KiB LDS, 2 blocks/CU ----------
// C[M,N] = A[M,K](bf16) * B[N,K](bf16)^T -> fp32.
// Rationale (rounds 0/2/5): 27% MfmaUtil plateau across both 1-block/CU 256²
// and its lockstep-phase variants; per-CU LDS traffic floor (13-15us) is
// serialized against MFMA by the intra-block barrier lockstep. Fix: give each
// CU a SECOND independent block (LDS 48KB, VGPR<=128 via launch_bounds) so one
// block's LDS bursts overlap the other's MFMA and tails stagger.
//
// Geometry: 512 thr = 8 waves (4M x 2N), wave tile 64x64; BK=32; 32 K-tiles.
// Per body (K-tile): 3 global_load_lds (A:2, B:1), 8 ds_read_b128, 16 MFMA,
// ONE vmcnt(0)+barrier. Stages for tile t+1 issue at the TOP of body t into
// the non-read buffer (WAR-safe: that buffer's reads were all consumed by
// MFMAs before the previous barrier), and drain at body end ~1300cyc later
// (covers ~900cyc HBM; the drain only ever waits on loads issued a full body
// earlier — avoids m230's 2ph failure of draining same-instant stages).
//
// LDS swizzle (derived for 64B row stride, 4 chunks of 16B):
//   slot = chunk ^ ((row>>1)&3)  -> per 16-lane fragment-read group the bank
//   quads (row*4+slot)%8 cover 0..7 exactly twice = uniform 2-way (free).
//   Applied on the GLOBAL source side for staging (LDS dst linear = tid*16B)
//   and on the chunk index of fragment reads. Frag chunk = quad (16x16x32
//   A/B layout: lane 16q+l16 holds elems k=8q..8q+7), C/D layout m89-verified
//   — both carried over from the round-2-verified kernel.
// Grid (64,8): h = by*64+bx -> h%8 = bx%8, so all 8 by-blocks sharing an
// A-slab land on one XCD (L2 reuse) with no explicit swizzle.

#define GLD16(SRC_, DST_)                                                     \
  __builtin_amdgcn_global_load_lds(                                           \
      (const __attribute__((address_space(1))) void*)(SRC_),                  \
      (__attribute__((address_space(3))) void*)(DST_), 16, 0, 0)

__global__ __launch_bounds__(512, 4) void gemm_bk32(
    const unsigned short* __restrict__ A,   // [M, K] bf16  (Xb)
    const unsigned short* __restrict__ B,   // [N, K] bf16  (Wb)
    float* __restrict__ C,                  // [M, N] fp32
    int M) {
    (void)M;
    constexpr int K = CIN;

    __shared__ __align__(16) unsigned short As[2 * 256 * 32];  // 32 KiB
    __shared__ __align__(16) unsigned short Bs[2 * 128 * 32];  // 16 KiB

    const int tid  = threadIdx.x;
    const int lane = tid & 63;
    const int w    = tid >> 6;
    const int q    = lane >> 4;          // quad 0..3
    const int l16  = lane & 15;
    const int sR   = (l16 >> 1) & 3;     // read-side swizzle term
    const int wm   = (w >> 1) * 64;      // wave row offset in 256
    const int wn   = (w & 1) * 64;       // wave col offset in 128

    const int rowA0 = blockIdx.x * 256;
    const int rowB0 = blockIdx.y * 128;

    // Staging map: thread t -> row=t>>2 (0..127), chunk-slot=t&3; source-side
    // swizzle c_data = slot ^ ((row>>1)&3) = (t&3) ^ ((t>>3)&3). LDS dst is
    // linear tid*16B per gload region. A gload1 covers rows +128 (row>>1
    // changes by 64 -> same &3 -> same c_data).
    const int stg_row = tid >> 2;
    const int c_data  = (tid & 3) ^ ((tid >> 3) & 3);
    const int tid8    = tid * 8;
    const unsigned short* pa = A + (size_t)(rowA0 + stg_row) * K + c_data * 8;
    const unsigned short* pb = B + (size_t)(rowB0 + stg_row) * K + c_data * 8;

    // Fragment read bases (chunk slot = q ^ sR, uniform across mf/nf).
    const int rslot8 = (q ^ sR) * 8;

    f32x4 acc[4][4] = {};                // 64 VGPR

#define STAGE(BUF_, KT_) do {                                                 \
    GLD16(pa + (KT_) * 32,                 As + (BUF_) * 8192 + tid8);        \
    GLD16(pa + (size_t)128 * K + (KT_) * 32, As + (BUF_) * 8192 + 4096 + tid8); \
    GLD16(pb + (KT_) * 32,                 Bs + (BUF_) * 4096 + tid8);        \
  } while (0)

#define BODY(BUF_) do {                                                       \
    bf16x8 af[4], bfr[4];                                                     \
    const unsigned short* ab_ = As + (BUF_) * 8192 + (wm + l16) * 32 + rslot8;\
    const unsigned short* bb_ = Bs + (BUF_) * 4096 + (wn + l16) * 32 + rslot8;\
    _Pragma("unroll")                                                         \
    for (int mf_ = 0; mf_ < 4; ++mf_) af[mf_]  = *(const bf16x8*)(ab_ + mf_ * 512); \
    _Pragma("unroll")                                                         \
    for (int nf_ = 0; nf_ < 4; ++nf_) bfr[nf_] = *(const bf16x8*)(bb_ + nf_ * 512); \
    _Pragma("unroll")                                                         \
    for (int mf_ = 0; mf_ < 4; ++mf_)                                         \
      _Pragma("unroll")                                                       \
      for (int nf_ = 0; nf_ < 4; ++nf_)                                       \
        acc[mf_][nf_] = __builtin_amdgcn_mfma_f32_16x16x32_bf16(              \
            af[mf_], bfr[nf_], acc[mf_][nf_], 0, 0, 0);                       \
  } while (0)

#define ENDBAR() do {                                                         \
    asm volatile("s_waitcnt vmcnt(0)" ::: "memory");                          \
    __builtin_amdgcn_s_barrier();                                             \
  } while (0)

    // ---- prologue: tile 0 -> buf0 ----
    STAGE(0, 0);
    ENDBAR();

    // ---- 32 K-tiles, 2 per iteration (static buf indices) ----
#pragma unroll 1
    for (int i = 0; i < 16; ++i) {
        const int t0 = 2 * i;
        // body t0 (reads buf0): stage t0+1 -> buf1 first (fire-and-forget DMA)
        STAGE(1, t0 + 1);
        BODY(0);
        ENDBAR();
        // body t0+1 (reads buf1): stage t0+2 -> buf0 (skip on last)
        if (i < 15) {
            STAGE(0, t0 + 2);
            BODY(1);
            ENDBAR();
        } else {
            BODY(1);                      // last tile: no stage, no barrier
        }
    }

    // ---- epilogue: C/D layout col = lane&15, row = quad*4 + r (m89-verified) ----
#pragma unroll
    for (int mf = 0; mf < 4; ++mf)
#pragma unroll
        for (int nf = 0; nf < 4; ++nf) {
            const int row0 = rowA0 + wm + mf * 16 + q * 4;
            float* cp = C + (size_t)row0 * COUT + rowB0 + wn + nf * 16 + l16;
#pragma unroll
            for (int r = 0; r < 4; ++r)
                cp[(size_t)r * COUT] = acc[mf][nf][r];
        }
#undef STAGE
#undef BODY
#undef ENDBAR
}

extern "C" void kernel_launch(void* const* d_in, const int* in_sizes, int n_in,
                              void* d_out, int out_size, void* d_ws, size_t ws_size,
                              hipStream_t stream) {
    const float* x    = (const float*)d_in[0];   // [M, CIN] fp32
    const float* vals = (const float*)d_in[1];   // [nnz] fp32
    const int*   idx  = (const int*)d_in[2];     // [2, nnz] int32

    float* out = (float*)d_out;                  // [M, COUT] fp32

    const int nnz = in_sizes[2] / 2;
    const int M   = in_sizes[0] / CIN;

    const size_t wf_bytes = (size_t)COUT * CIN * sizeof(float);          // 4 MB
    const size_t wb_bytes = (size_t)COUT * CIN * sizeof(unsigned short); // 2 MB

    float*          Wf = (float*)d_ws;
    unsigned short* Wb = (unsigned short*)((char*)d_ws + wf_bytes);
    unsigned short* Xb = (unsigned short*)((char*)d_ws + wf_bytes + wb_bytes);

    // 1) zero fp32 W (ws is poisoned 0xAA before every call)
    zero_f32<<<dim3(COUT * CIN / (256 * 4)), dim3(256), 0, stream>>>((float4*)Wf);
    // 2) scatter-add duplicates like coalesce()
    scatter_add<<<dim3((nnz + 255) / 256), dim3(256), 0, stream>>>(vals, idx, idx + nnz, Wf, nnz);
    // 3) W -> bf16
    cvt_bf16_bulk<<<dim3(COUT * CIN / (256 * 8)), dim3(256), 0, stream>>>(Wf, Wb);
    // 4) x -> bf16 (compression pass; see note on kernel 3)
    cvt_bf16_bulk<<<dim3((unsigned)((size_t)M * CIN / (256 * 8))), dim3(256), 0, stream>>>(x, Xb);
    // 5) GEMM: out = x @ W^T.  grid (64, 8) = 512 blocks = 2/CU (48 KiB LDS).
    gemm_bk32<<<dim3(M / 256, COUT / 128), dim3(512), 0, stream>>>(Xb, Wb, out, M);
}

// Round 7
// 169.010 us; speedup vs baseline: 1.5337x; 1.5337x over previous
//
#include <hip/hip_runtime.h>
#include <cstdint>
#include <cstddef>

// Problem constants: W is [COUT, CIN]; x is [4*4096, CIN]. All I/O fp32.
#define CIN  1024
#define COUT 1024

typedef __attribute__((ext_vector_type(8))) short bf16x8;
typedef __attribute__((ext_vector_type(4))) float f32x4;

// ---------- fp32 -> bf16 (round-to-nearest-even) ----------
__device__ __forceinline__ unsigned short f2bf(float f) {
    union { float f; unsigned int i; } v;
    v.f = f;
    unsigned int u = v.i;
    u += 0x7FFFu + ((u >> 16) & 1u);
    return (unsigned short)(u >> 16);
}

__device__ __forceinline__ void cvt8(const float* __restrict__ s,
                                     unsigned short* __restrict__ d) {
    float4 v0 = *(const float4*)s;
    float4 v1 = *(const float4*)(s + 4);
    union { bf16x8 v; unsigned short u[8]; } w;
    w.u[0] = f2bf(v0.x); w.u[1] = f2bf(v0.y); w.u[2] = f2bf(v0.z); w.u[3] = f2bf(v0.w);
    w.u[4] = f2bf(v1.x); w.u[5] = f2bf(v1.y); w.u[6] = f2bf(v1.z); w.u[7] = f2bf(v1.w);
    *(bf16x8*)d = w.v;
}

// ---------- kernel 1: fused {zero Wf} || {cvt x -> bf16} (independent jobs) ----
// blocks [0,1024): zero the 4MB fp32 W accumulator (1024*256 float4).
// blocks [1024,9216): convert x (16384x1024 fp32) to bf16, 8 elems/thread.
__global__ void prep_zero_cvtx(float4* __restrict__ Wf4,
                               const float* __restrict__ x,
                               unsigned short* __restrict__ Xb) {
    const int b = blockIdx.x;
    if (b < 1024) {
        Wf4[(size_t)b * 256 + threadIdx.x] = float4{0.f, 0.f, 0.f, 0.f};
    } else {
        const size_t i = (((size_t)(b - 1024) * 256) + threadIdx.x) * 8;
        cvt8(x + i, Xb + i);
    }
}

// ---------- kernel 2: scatter-add fp32 COO values into dense fp32 W ----------
__global__ void scatter_add(const float* __restrict__ vals,
                            const int* __restrict__ rows,
                            const int* __restrict__ cols,
                            float* __restrict__ W, int nnz) {
    int i = blockIdx.x * 256 + threadIdx.x;
    if (i < nnz) {
        atomicAdd(W + (size_t)rows[i] * CIN + cols[i], vals[i]);
    }
}

// ---------- kernel 3: fp32 -> bf16 bulk convert (W) ----------
// Round-4 lesson: the x compression pass is NOT overhead (A-stream is shared;
// fusing the cvt into the GEMM doubled L3 traffic, +40us). Keep bf16 operands.
__global__ void cvt_bf16_bulk(const float* __restrict__ src, unsigned short* __restrict__ dst) {
    size_t i = ((size_t)blockIdx.x * 256 + threadIdx.x) * 8;
    cvt8(src + i, dst + i);
}

// ---------- kernel 4: 128x128-tile GEMM, BK=32, 3-buffer, 3 blocks/CU ----------
// C[M,N] = A[M,K](bf16) * B[N,K](bf16)^T -> fp32.
// Round-6 post-mortem: launch_bounds(512,4) capped regs at 128/wave -> spill
// (WRITE 369MB). Fix: 256 thr = 4 waves (2Mx2N, wave tile 64x64), 3 buffers
// x 16KB = 48KB LDS -> 3 blocks/CU (LDS-limited), reg budget 512/3 = 170 >=
// ~120 used -> no spill pressure. De-lockstep mechanism: 3 independent
// blocks per CU fill each other's stage/barrier gaps with MFMA; grid 1024 >
// 768 co-resident overlaps C-write tails with the 4th scheduling round.
//
// Pipeline (2-deep, never drains a same-body stage):
//   prologue: STAGE(buf0,t0) STAGE(buf1,t1); vmcnt(4); barrier
//   body t (reads buf t%3): STAGE((t+2)%3, t+2); 8x ds_read frags; 16 MFMA;
//                           vmcnt(4) [= stage t+1 complete, issued one full
//                           body (~1000cyc) earlier]; barrier
//   t=30: no stage, vmcnt(0); t=31: no wait.
//   WAR: stage target (t+2)%3 == buf of body t-1, whose ds_reads retired
//   before body t-1's end barrier (MFMA operands force lgkm completion).
//
// Data maps carried over from the round-6 kernel (which PASSED correctness):
//   staging: thread t -> row=t>>2, chunk c_data=(t&3)^((t>>3)&3) (source-side
//   swizzle; LDS dst linear = tid*16B; +64-row gload has same swizzle term);
//   frag read: chunk slot = q ^ ((l16>>1)&3)  (measured 0 bank conflicts);
//   frag chunk = quad (lane 16q+l holds k=8q..8q+7); C/D: col=l16, row=q*4+r.

#define GLD16(SRC_, DST_)                                                     \
  __builtin_amdgcn_global_load_lds(                                           \
      (const __attribute__((address_space(1))) void*)(SRC_),                  \
      (__attribute__((address_space(3))) void*)(DST_), 16, 0, 0)

__global__ __launch_bounds__(256, 3) void gemm_3buf(
    const unsigned short* __restrict__ A,   // [M, K] bf16  (Xb)
    const unsigned short* __restrict__ B,   // [N, K] bf16  (Wb)
    float* __restrict__ C,                  // [M, N] fp32
    int M) {
    (void)M;
    constexpr int K = CIN;

    __shared__ __align__(16) unsigned short As[3 * 128 * 32];  // 24 KiB
    __shared__ __align__(16) unsigned short Bs[3 * 128 * 32];  // 24 KiB

    const int tid  = threadIdx.x;
    const int lane = tid & 63;
    const int w    = tid >> 6;           // 4 waves
    const int q    = lane >> 4;          // quad 0..3
    const int l16  = lane & 15;
    const int sR   = (l16 >> 1) & 3;     // read-side swizzle term
    const int wm   = (w >> 1) * 64;      // wave row offset in 128
    const int wn   = (w & 1) * 64;       // wave col offset in 128

    const int rowA0 = blockIdx.x * 128;
    const int rowB0 = blockIdx.y * 128;

    // Staging map: thread t -> row=t>>2 (0..63 per gload), slot=t&3;
    // source swizzle c_data = (t&3)^((t>>3)&3); second gload covers rows+64
    // (row>>1 changes by 32 -> same &3 -> same swizzle term).
    const int stg_row = tid >> 2;
    const int c_data  = (tid & 3) ^ ((tid >> 3) & 3);
    const int tid8    = tid * 8;
    const unsigned short* pa = A + (size_t)(rowA0 + stg_row) * K + c_data * 8;
    const unsigned short* pb = B + (size_t)(rowB0 + stg_row) * K + c_data * 8;

    const int rslot8 = (q ^ sR) * 8;     // fragment chunk offset (elements)

    f32x4 acc[4][4] = {};                // 64 VGPR

#define STAGE(BUF_, KT_) do {                                                 \
    GLD16(pa + (KT_) * 32,                   As + (BUF_) * 4096 + tid8);      \
    GLD16(pa + (size_t)64 * K + (KT_) * 32,  As + (BUF_) * 4096 + 2048 + tid8); \
    GLD16(pb + (KT_) * 32,                   Bs + (BUF_) * 4096 + tid8);      \
    GLD16(pb + (size_t)64 * K + (KT_) * 32,  Bs + (BUF_) * 4096 + 2048 + tid8); \
  } while (0)

#define BODY(BUFOFF_) do {                                                    \
    bf16x8 af[4], bfr[4];                                                     \
    const unsigned short* ab_ = As + (BUFOFF_) + (wm + l16) * 32 + rslot8;    \
    const unsigned short* bb_ = Bs + (BUFOFF_) + (wn + l16) * 32 + rslot8;    \
    _Pragma("unroll")                                                         \
    for (int mf_ = 0; mf_ < 4; ++mf_) af[mf_]  = *(const bf16x8*)(ab_ + mf_ * 512); \
    _Pragma("unroll")                                                         \
    for (int nf_ = 0; nf_ < 4; ++nf_) bfr[nf_] = *(const bf16x8*)(bb_ + nf_ * 512); \
    __builtin_amdgcn_s_setprio(1);                                            \
    _Pragma("unroll")                                                         \
    for (int mf_ = 0; mf_ < 4; ++mf_)                                         \
      _Pragma("unroll")                                                       \
      for (int nf_ = 0; nf_ < 4; ++nf_)                                       \
        acc[mf_][nf_] = __builtin_amdgcn_mfma_f32_16x16x32_bf16(              \
            af[mf_], bfr[nf_], acc[mf_][nf_], 0, 0, 0);                       \
    __builtin_amdgcn_s_setprio(0);                                            \
  } while (0)

    // ---- prologue: tiles 0,1 -> buf 0,1 ----
    STAGE(0, 0); STAGE(1, 1);
    asm volatile("s_waitcnt vmcnt(4)" ::: "memory");   // tile0 complete
    __builtin_amdgcn_s_barrier();

    int rb = 0;                          // read-buffer index (0,1,2 rotating)
#pragma unroll 1
    for (int t = 0; t < 30; ++t) {
        const int sb = (rb == 0) ? 2 : rb - 1;        // (rb+2)%3
        STAGE(sb, t + 2);
        BODY(rb * 4096);
        asm volatile("s_waitcnt vmcnt(4)" ::: "memory");  // stage t+1 done
        __builtin_amdgcn_s_barrier();
        rb = (rb == 2) ? 0 : rb + 1;
    }
    // t = 30: no stage; drain stage(31)
    BODY(rb * 4096);
    asm volatile("s_waitcnt vmcnt(0)" ::: "memory");
    __builtin_amdgcn_s_barrier();
    rb = (rb == 2) ? 0 : rb + 1;
    // t = 31: last tile, no wait
    BODY(rb * 4096);

    // ---- epilogue: C/D layout col = lane&15, row = quad*4 + r ----
#pragma unroll
    for (int mf = 0; mf < 4; ++mf)
#pragma unroll
        for (int nf = 0; nf < 4; ++nf) {
            const int row0 = rowA0 + wm + mf * 16 + q * 4;
            float* cp = C + (size_t)row0 * COUT + rowB0 + wn + nf * 16 + l16;
#pragma unroll
            for (int r = 0; r < 4; ++r)
                cp[(size_t)r * COUT] = acc[mf][nf][r];
        }
#undef STAGE
#undef BODY
}

extern "C" void kernel_launch(void* const* d_in, const int* in_sizes, int n_in,
                              void* d_out, int out_size, void* d_ws, size_t ws_size,
                              hipStream_t stream) {
    const float* x    = (const float*)d_in[0];   // [M, CIN] fp32
    const float* vals = (const float*)d_in[1];   // [nnz] fp32
    const int*   idx  = (const int*)d_in[2];     // [2, nnz] int32

    float* out = (float*)d_out;                  // [M, COUT] fp32

    const int nnz = in_sizes[2] / 2;
    const int M   = in_sizes[0] / CIN;

    const size_t wf_bytes = (size_t)COUT * CIN * sizeof(float);          // 4 MB
    const size_t wb_bytes = (size_t)COUT * CIN * sizeof(unsigned short); // 2 MB

    float*          Wf = (float*)d_ws;
    unsigned short* Wb = (unsigned short*)((char*)d_ws + wf_bytes);
    unsigned short* Xb = (unsigned short*)((char*)d_ws + wf_bytes + wb_bytes);

    const unsigned zero_blocks = COUT * CIN / (256 * 4);                 // 1024
    const unsigned cvtx_blocks = (unsigned)((size_t)M * CIN / (256 * 8)); // 8192

    // 1) fused: zero fp32 W || x -> bf16 (independent)
    prep_zero_cvtx<<<dim3(zero_blocks + cvtx_blocks), dim3(256), 0, stream>>>(
        (float4*)Wf, x, Xb);
    // 2) scatter-add duplicates like coalesce()
    scatter_add<<<dim3((nnz + 255) / 256), dim3(256), 0, stream>>>(vals, idx, idx + nnz, Wf, nnz);
    // 3) W -> bf16
    cvt_bf16_bulk<<<dim3(COUT * CIN / (256 * 8)), dim3(256), 0, stream>>>(Wf, Wb);
    // 4) GEMM: out = x @ W^T.  grid (128, 8) = 1024 blocks, 3/CU resident.
    gemm_3buf<<<dim3(M / 128, COUT / 128), dim3(256), 0, stream>>>(Xb, Wb, out, M);
}

// Round 8
// 155.440 us; speedup vs baseline: 1.6676x; 1.0873x over previous
//
#include <hip/hip_runtime.h>
#include <cstdint>
#include <cstddef>

// Problem constants: W is [COUT, CIN]; x is [4*4096, CIN]. All I/O fp32.
#define CIN  1024
#define COUT 1024

typedef __attribute__((ext_vector_type(8))) short bf16x8;
typedef __attribute__((ext_vector_type(4))) float f32x4;

// ---------- fp32 -> bf16 (round-to-nearest-even) ----------
__device__ __forceinline__ unsigned short f2bf(float f) {
    union { float f; unsigned int i; } v;
    v.f = f;
    unsigned int u = v.i;
    u += 0x7FFFu + ((u >> 16) & 1u);
    return (unsigned short)(u >> 16);
}

__device__ __forceinline__ void cvt8(const float* __restrict__ s,
                                     unsigned short* __restrict__ d) {
    float4 v0 = *(const float4*)s;
    float4 v1 = *(const float4*)(s + 4);
    union { bf16x8 v; unsigned short u[8]; } w;
    w.u[0] = f2bf(v0.x); w.u[1] = f2bf(v0.y); w.u[2] = f2bf(v0.z); w.u[3] = f2bf(v0.w);
    w.u[4] = f2bf(v1.x); w.u[5] = f2bf(v1.y); w.u[6] = f2bf(v1.z); w.u[7] = f2bf(v1.w);
    *(bf16x8*)d = w.v;
}

// ---------- kernel 1: zero the fp32 W accumulation buffer ----------
__global__ void zero_f32(float4* __restrict__ p) {
    p[blockIdx.x * 256 + threadIdx.x] = float4{0.f, 0.f, 0.f, 0.f};
}

// ---------- kernel 2: fused {scatter-add into Wf} || {cvt x -> bf16} ----------
// Independent jobs (scatter touches Wf, cvtx touches x/Xb); the ~3us scatter
// hides under the ~15us BW-bound cvtx. zero_f32 must precede (prior launch).
__global__ void scatter_cvtx(const float* __restrict__ vals,
                             const int* __restrict__ rows,
                             const int* __restrict__ cols,
                             float* __restrict__ W, int nnz, int nsb,
                             const float* __restrict__ x,
                             unsigned short* __restrict__ Xb) {
    const int b = blockIdx.x;
    if (b < nsb) {
        const int i = b * 256 + threadIdx.x;
        if (i < nnz) atomicAdd(W + (size_t)rows[i] * CIN + cols[i], vals[i]);
    } else {
        const size_t i = (((size_t)(b - nsb) * 256) + threadIdx.x) * 8;
        cvt8(x + i, Xb + i);
    }
}

// ---------- kernel 3: fp32 -> bf16 bulk convert (W) ----------
// Round-4 lesson: the x compression pass is NOT overhead (A-stream is shared;
// fusing the cvt into the GEMM doubled L3 traffic, +40us). Keep bf16 operands.
__global__ void cvt_bf16_bulk(const float* __restrict__ src, unsigned short* __restrict__ dst) {
    size_t i = ((size_t)blockIdx.x * 256 + threadIdx.x) * 8;
    cvt8(src + i, dst + i);
}

// ---------- kernel 4: 256x256 8-phase GEMM (r2-verified) + peeled last iter ----
// C[M,N] = A[M,K](bf16) * B[N,K](bf16)^T -> fp32.
// Main loop = round-2 v2 schedule VERBATIM for i=0..6 (stage guards drop out);
// iteration 7 peeled: phases q1-q4 as v2 (K1 = vmcnt(0), publishes buf1), then
// q5-q8 barrier-free (buf1 fully published, no writers) with each C-quadrant's
// stores issued right after its FINAL MFMA:
//   q5: MFMA(0,0) -> store quad(0,0);  q6: MFMA(0,1) -> store quad(0,1);
//   q7: MFMA(1,0) -> store quad(1,0);  q8: MFMA(1,1) -> store quad(1,1).
// Mechanism: the 64MB C-tail (10us at HBM BW, fully exposed at 1 block/CU)
// starts draining under the last ~4.5us of MFMA. i=7 has no stages, so no
// vmcnt ever counts the stores. Data dep (stores read acc) orders them after
// their MFMA; store->MFMA anti-ordering not needed (different registers).
// All data maps r2-verified: staging swizzle chunk^(row&7) on the global
// source (linear LDS dst), fragment chunk (ks*4+quad)^s7, C/D col=l16,
// row=quad*4+r.

#define GLD16(SRC_, DST_)                                                     \
  __builtin_amdgcn_global_load_lds(                                           \
      (const __attribute__((address_space(1))) void*)(SRC_),                  \
      (__attribute__((address_space(3))) void*)(DST_), 16, 0, 0)

#define STAGE_A(BUF_, HALF_, KT_) do {                                        \
    GLD16(pa + (size_t)((HALF_) * 128)      * CIN + (size_t)(KT_) * 64,       \
          As + (BUF_) * 16384 + ((HALF_) * 128) * 64 + tid8);                 \
    GLD16(pa + (size_t)((HALF_) * 128 + 64) * CIN + (size_t)(KT_) * 64,       \
          As + (BUF_) * 16384 + ((HALF_) * 128 + 64) * 64 + tid8);            \
  } while (0)

#define STAGE_B(BUF_, HALF_, KT_) do {                                        \
    GLD16(pb + (size_t)((HALF_) * 128)      * CIN + (size_t)(KT_) * 64,       \
          Bs + (BUF_) * 16384 + ((HALF_) * 128) * 64 + tid8);                 \
    GLD16(pb + (size_t)((HALF_) * 128 + 64) * CIN + (size_t)(KT_) * 64,       \
          Bs + (BUF_) * 16384 + ((HALF_) * 128 + 64) * 64 + tid8);            \
  } while (0)

#define LOAD_A(BUF_, QA_) do {                                                \
    const unsigned short* ab_ = As + (BUF_) * 16384 + ((QA_) * 128 + wm64) * 64; \
    _Pragma("unroll")                                                         \
    for (int ks_ = 0; ks_ < 2; ++ks_) {                                       \
      const int cx_ = ((ks_ * 4 + quad) ^ s7) * 8;                            \
      _Pragma("unroll")                                                       \
      for (int mf_ = 0; mf_ < 4; ++mf_)                                       \
        af[ks_][mf_] = *(const bf16x8*)(ab_ + (mf_ * 16 + l16) * 64 + cx_);   \
    }                                                                         \
  } while (0)

#define LOAD_B(BUF_, QB_, DST_) do {                                          \
    const unsigned short* bb_ = Bs + (BUF_) * 16384 + ((QB_) * 128 + wn32) * 64; \
    _Pragma("unroll")                                                         \
    for (int ks_ = 0; ks_ < 2; ++ks_) {                                       \
      const int cx_ = ((ks_ * 4 + quad) ^ s7) * 8;                            \
      _Pragma("unroll")                                                       \
      for (int nf_ = 0; nf_ < 2; ++nf_)                                       \
        DST_[ks_][nf_] = *(const bf16x8*)(bb_ + (nf_ * 16 + l16) * 64 + cx_); \
    }                                                                         \
  } while (0)

#define MFMA_Q(QA_, QB_, BF_)                                                 \
    _Pragma("unroll")                                                         \
    for (int ks_ = 0; ks_ < 2; ++ks_)                                         \
      _Pragma("unroll")                                                       \
      for (int mf_ = 0; mf_ < 4; ++mf_)                                       \
        _Pragma("unroll")                                                     \
        for (int nf_ = 0; nf_ < 2; ++nf_)                                     \
          acc[QA_][QB_][mf_][nf_] = __builtin_amdgcn_mfma_f32_16x16x32_bf16(  \
              af[ks_][mf_], BF_[ks_][nf_], acc[QA_][QB_][mf_][nf_], 0, 0, 0)

#define WRITE_CQ(QA_, QB_) do {                                               \
    _Pragma("unroll")                                                         \
    for (int mf_ = 0; mf_ < 4; ++mf_)                                         \
      _Pragma("unroll")                                                       \
      for (int nf_ = 0; nf_ < 2; ++nf_) {                                     \
        const int row0_ = rowA0 + (QA_) * 128 + wm64 + mf_ * 16 + quad * 4;   \
        float* cp_ = C + (size_t)row0_ * COUT                                 \
                       + rowB0 + (QB_) * 128 + wn32 + nf_ * 16 + l16;         \
        _Pragma("unroll")                                                     \
        for (int r_ = 0; r_ < 4; ++r_)                                        \
            cp_[(size_t)r_ * COUT] = acc[QA_][QB_][mf_][nf_][r_];             \
      }                                                                       \
  } while (0)

#define SYNC_PRE() do {                                                       \
    __builtin_amdgcn_s_barrier();                                             \
    asm volatile("s_waitcnt lgkmcnt(0)" ::: "memory");                        \
    __builtin_amdgcn_sched_barrier(0);                                        \
    __builtin_amdgcn_s_setprio(1);                                            \
  } while (0)

#define SYNC_POST() __builtin_amdgcn_s_setprio(0)

// Barrier-free variant for the peeled tail (no LDS writers remain).
#define WAIT_LGKM() do {                                                      \
    asm volatile("s_waitcnt lgkmcnt(0)" ::: "memory");                        \
    __builtin_amdgcn_sched_barrier(0);                                        \
  } while (0)

__global__ __launch_bounds__(512, 2) void gemm_8ph_peel(
    const unsigned short* __restrict__ A,   // [M, K] bf16
    const unsigned short* __restrict__ B,   // [N, K] bf16
    float* __restrict__ C,                  // [M, N] fp32
    int M) {
    (void)M;
    constexpr int K = CIN;

    __shared__ __align__(16) unsigned short As[2 * 16384];  // 2 x [256][64]
    __shared__ __align__(16) unsigned short Bs[2 * 16384];

    const int tid  = threadIdx.x;
    const int lane = tid & 63;
    const int w    = tid >> 6;
    const int quad = lane >> 4;
    const int l16  = lane & 15;
    const int s7   = l16 & 7;
    const int wm64 = (w >> 2) * 64;
    const int wn32 = (w & 3) * 32;

    const int rowA0 = blockIdx.x * 256;
    const int rowB0 = blockIdx.y * 256;

    const int stg_row = tid >> 3;
    const int c_data  = (tid & 7) ^ (stg_row & 7);
    const int tid8    = tid * 8;
    const unsigned short* pa = A + (size_t)(rowA0 + stg_row) * K + c_data * 8;
    const unsigned short* pb = B + (size_t)(rowB0 + stg_row) * K + c_data * 8;

    f32x4 acc[2][2][4][2] = {};

    // ---- prologue: tile0 -> buf0 (A0,B0,B1,A1), tile1 -> buf1 (A0,B0) ----
    STAGE_A(0, 0, 0); STAGE_B(0, 0, 0); STAGE_B(0, 1, 0); STAGE_A(0, 1, 0);
    STAGE_A(1, 0, 1); STAGE_B(1, 0, 1);
    asm volatile("s_waitcnt vmcnt(4)" ::: "memory");  // tile0 complete
    __builtin_amdgcn_s_barrier();

#pragma unroll 1
    for (int i = 0; i < 7; ++i) {          // steady-state: all stages unconditional
        const int k1 = 2 * i + 1;          // <= 13
        const int k2 = 2 * i + 2;          // <= 14
        const int k3 = 2 * i + 3;          // <= 15

        bf16x8 af[2][4];
        bf16x8 bf0[2][2], bf1[2][2];

        // even tile (buf0)
        LOAD_A(0, 0); LOAD_B(0, 0, bf0);
        STAGE_B(1, 1, k1);
        SYNC_PRE(); MFMA_Q(0, 0, bf0); SYNC_POST();
        __builtin_amdgcn_s_barrier();

        LOAD_B(0, 1, bf1);
        STAGE_A(1, 1, k1);
        SYNC_PRE(); MFMA_Q(0, 1, bf1); SYNC_POST();
        __builtin_amdgcn_s_barrier();

        LOAD_A(0, 1);
        STAGE_A(0, 0, k2);
        SYNC_PRE(); MFMA_Q(1, 0, bf0); SYNC_POST();
        __builtin_amdgcn_s_barrier();

        STAGE_B(0, 0, k2);
        SYNC_PRE(); MFMA_Q(1, 1, bf1); SYNC_POST();
        asm volatile("s_waitcnt vmcnt(4)" ::: "memory");   // K1: odd tile ready
        __builtin_amdgcn_s_barrier();

        // odd tile (buf1)
        LOAD_A(1, 0); LOAD_B(1, 0, bf0);
        STAGE_B(0, 1, k2);
        SYNC_PRE(); MFMA_Q(0, 0, bf0); SYNC_POST();
        __builtin_amdgcn_s_barrier();

        LOAD_B(1, 1, bf1);
        STAGE_A(0, 1, k2);
        SYNC_PRE(); MFMA_Q(0, 1, bf1); SYNC_POST();
        __builtin_amdgcn_s_barrier();

        LOAD_A(1, 1);
        STAGE_A(1, 0, k3);
        SYNC_PRE(); MFMA_Q(1, 0, bf0); SYNC_POST();
        __builtin_amdgcn_s_barrier();

        STAGE_B(1, 0, k3);
        SYNC_PRE(); MFMA_Q(1, 1, bf1); SYNC_POST();
        asm volatile("s_waitcnt vmcnt(4)" ::: "memory");   // K2: even tile ready
        __builtin_amdgcn_s_barrier();
    }

    // ---- peeled i=7: tiles 14 (buf0) and 15 (buf1) ----
    {
        bf16x8 af[2][4];
        bf16x8 bf0[2][2], bf1[2][2];

        // q1..q4: even tile (buf0), v2 structure; K1 = vmcnt(0) publishes buf1
        LOAD_A(0, 0); LOAD_B(0, 0, bf0);
        STAGE_B(1, 1, 15);
        SYNC_PRE(); MFMA_Q(0, 0, bf0); SYNC_POST();
        __builtin_amdgcn_s_barrier();

        LOAD_B(0, 1, bf1);
        STAGE_A(1, 1, 15);
        SYNC_PRE(); MFMA_Q(0, 1, bf1); SYNC_POST();
        __builtin_amdgcn_s_barrier();

        LOAD_A(0, 1);
        SYNC_PRE(); MFMA_Q(1, 0, bf0); SYNC_POST();
        __builtin_amdgcn_s_barrier();

        SYNC_PRE(); MFMA_Q(1, 1, bf1); SYNC_POST();
        asm volatile("s_waitcnt vmcnt(0)" ::: "memory");   // buf1 fully published
        __builtin_amdgcn_s_barrier();

        // q5..q8: odd tile (buf1), barrier-free; store each C-quadrant as it
        // finalizes so the 64MB tail drains under the remaining MFMA.
        LOAD_A(1, 0); LOAD_B(1, 0, bf0); LOAD_B(1, 1, bf1);
        WAIT_LGKM();
        __builtin_amdgcn_s_setprio(1); MFMA_Q(0, 0, bf0); __builtin_amdgcn_s_setprio(0);
        WRITE_CQ(0, 0);

        __builtin_amdgcn_s_setprio(1); MFMA_Q(0, 1, bf1); __builtin_amdgcn_s_setprio(0);
        WRITE_CQ(0, 1);

        LOAD_A(1, 1);
        WAIT_LGKM();
        __builtin_amdgcn_s_setprio(1); MFMA_Q(1, 0, bf0); __builtin_amdgcn_s_setprio(0);
        WRITE_CQ(1, 0);

        __builtin_amdgcn_s_setprio(1); MFMA_Q(1, 1, bf1); __builtin_amdgcn_s_setprio(0);
        WRITE_CQ(1, 1);
    }
}

extern "C" void kernel_launch(void* const* d_in, const int* in_sizes, int n_in,
                              void* d_out, int out_size, void* d_ws, size_t ws_size,
                              hipStream_t stream) {
    const float* x    = (const float*)d_in[0];   // [M, CIN] fp32
    const float* vals = (const float*)d_in[1];   // [nnz] fp32
    const int*   idx  = (const int*)d_in[2];     // [2, nnz] int32

    float* out = (float*)d_out;                  // [M, COUT] fp32

    const int nnz = in_sizes[2] / 2;
    const int M   = in_sizes[0] / CIN;

    const size_t wf_bytes = (size_t)COUT * CIN * sizeof(float);          // 4 MB
    const size_t wb_bytes = (size_t)COUT * CIN * sizeof(unsigned short); // 2 MB

    float*          Wf = (float*)d_ws;
    unsigned short* Wb = (unsigned short*)((char*)d_ws + wf_bytes);
    unsigned short* Xb = (unsigned short*)((char*)d_ws + wf_bytes + wb_bytes);

    const int nsb = (nnz + 255) / 256;                                    // 512
    const unsigned cvtx_blocks = (unsigned)((size_t)M * CIN / (256 * 8)); // 8192

    // 1) zero fp32 W (ws is poisoned 0xAA before every call)
    zero_f32<<<dim3(COUT * CIN / (256 * 4)), dim3(256), 0, stream>>>((float4*)Wf);
    // 2) scatter-add (needs zeroed W) || x -> bf16 (independent) in one launch
    scatter_cvtx<<<dim3((unsigned)nsb + cvtx_blocks), dim3(256), 0, stream>>>(
        vals, idx, idx + nnz, Wf, nnz, nsb, x, Xb);
    // 3) W -> bf16
    cvt_bf16_bulk<<<dim3(COUT * CIN / (256 * 8)), dim3(256), 0, stream>>>(Wf, Wb);
    // 4) GEMM with peeled, store-interleaved last iteration: out = x @ W^T.
    gemm_8ph_peel<<<dim3(M / 256, COUT / 256), dim3(512), 0, stream>>>(Xb, Wb, out, M);
}

// Round 9
// 155.001 us; speedup vs baseline: 1.6723x; 1.0028x over previous
//
#include <hip/hip_runtime.h>
#include <cstdint>
#include <cstddef>

// Problem constants: W is [COUT, CIN]; x is [4*4096, CIN]. All I/O fp32.
#define CIN  1024
#define COUT 1024

typedef __attribute__((ext_vector_type(8))) short bf16x8;
typedef __attribute__((ext_vector_type(4))) float f32x4;

// ---------- fp32 -> bf16 (round-to-nearest-even) ----------
__device__ __forceinline__ unsigned short f2bf(float f) {
    union { float f; unsigned int i; } v;
    v.f = f;
    unsigned int u = v.i;
    u += 0x7FFFu + ((u >> 16) & 1u);
    return (unsigned short)(u >> 16);
}

__device__ __forceinline__ void cvt8(const float* __restrict__ s,
                                     unsigned short* __restrict__ d) {
    float4 v0 = *(const float4*)s;
    float4 v1 = *(const float4*)(s + 4);
    union { bf16x8 v; unsigned short u[8]; } w;
    w.u[0] = f2bf(v0.x); w.u[1] = f2bf(v0.y); w.u[2] = f2bf(v0.z); w.u[3] = f2bf(v0.w);
    w.u[4] = f2bf(v1.x); w.u[5] = f2bf(v1.y); w.u[6] = f2bf(v1.z); w.u[7] = f2bf(v1.w);
    *(bf16x8*)d = w.v;
}

// ---------- kernel 1: zero the fp32 W accumulation buffer ----------
__global__ void zero_f32(float4* __restrict__ p) {
    p[blockIdx.x * 256 + threadIdx.x] = float4{0.f, 0.f, 0.f, 0.f};
}

// ---------- kernel 2: fused {scatter-add into Wf} || {cvt x -> bf16} ----------
__global__ void scatter_cvtx(const float* __restrict__ vals,
                             const int* __restrict__ rows,
                             const int* __restrict__ cols,
                             float* __restrict__ W, int nnz, int nsb,
                             const float* __restrict__ x,
                             unsigned short* __restrict__ Xb) {
    const int b = blockIdx.x;
    if (b < nsb) {
        const int i = b * 256 + threadIdx.x;
        if (i < nnz) atomicAdd(W + (size_t)rows[i] * CIN + cols[i], vals[i]);
    } else {
        const size_t i = (((size_t)(b - nsb) * 256) + threadIdx.x) * 8;
        cvt8(x + i, Xb + i);
    }
}

// ---------- kernel 3: fp32 -> bf16 bulk convert (W) ----------
// Round-4 lesson: the x compression pass is NOT overhead (A-stream is shared;
// fusing the cvt into the GEMM doubled L3 traffic, +40us). Keep bf16 operands.
__global__ void cvt_bf16_bulk(const float* __restrict__ src, unsigned short* __restrict__ dst) {
    size_t i = ((size_t)blockIdx.x * 256 + threadIdx.x) * 8;
    cvt8(src + i, dst + i);
}

// ---------- kernel 4: 256x256 8-phase GEMM + peeled last iter, v4 ----------
// v4 (single variable vs round-8): REMOVE the forced per-phase lgkmcnt(0)
// drain + sched_barrier(0) pin. Rationale: ds_reads here are plain C++ loads,
// so the compiler tracks read->MFMA dataflow and emits fine-grained
// lgkmcnt(N) waits (m97: near-optimal), letting reads overlap MFMA within a
// phase instead of the serialized [12 reads][drain-all][16 MFMA]. LDS-pipe
// accounting: 2816cyc/K-tile LDS vs 620cyc/SIMD MFMA -> LDS is the binding
// pipe at ~59% util; the forced drain is the in-wave serializer.
// Safety (unchanged memory contract): every LOAD is consumed by a same-phase
// MFMA (consumption forces retirement), and all WAR/publish arguments key off
// the phase-END barrier + own-wave vmcnt checkpoints, not the drain.
// Everything else identical to round-8 (which passed, absmax 0.25):
//   - main loop i=0..6 unconditional stages; peel i=7 with per-quadrant
//     C-stores after each final MFMA (tail drains under remaining MFMA);
//   - staging swizzle chunk^(row&7) on the global source (linear LDS dst);
//   - fragment chunk (ks*4+quad)^s7; C/D col=l16, row=quad*4+r (m89).

#define GLD16(SRC_, DST_)                                                     \
  __builtin_amdgcn_global_load_lds(                                           \
      (const __attribute__((address_space(1))) void*)(SRC_),                  \
      (__attribute__((address_space(3))) void*)(DST_), 16, 0, 0)

#define STAGE_A(BUF_, HALF_, KT_) do {                                        \
    GLD16(pa + (size_t)((HALF_) * 128)      * CIN + (size_t)(KT_) * 64,       \
          As + (BUF_) * 16384 + ((HALF_) * 128) * 64 + tid8);                 \
    GLD16(pa + (size_t)((HALF_) * 128 + 64) * CIN + (size_t)(KT_) * 64,       \
          As + (BUF_) * 16384 + ((HALF_) * 128 + 64) * 64 + tid8);            \
  } while (0)

#define STAGE_B(BUF_, HALF_, KT_) do {                                        \
    GLD16(pb + (size_t)((HALF_) * 128)      * CIN + (size_t)(KT_) * 64,       \
          Bs + (BUF_) * 16384 + ((HALF_) * 128) * 64 + tid8);                 \
    GLD16(pb + (size_t)((HALF_) * 128 + 64) * CIN + (size_t)(KT_) * 64,       \
          Bs + (BUF_) * 16384 + ((HALF_) * 128 + 64) * 64 + tid8);            \
  } while (0)

#define LOAD_A(BUF_, QA_) do {                                                \
    const unsigned short* ab_ = As + (BUF_) * 16384 + ((QA_) * 128 + wm64) * 64; \
    _Pragma("unroll")                                                         \
    for (int ks_ = 0; ks_ < 2; ++ks_) {                                       \
      const int cx_ = ((ks_ * 4 + quad) ^ s7) * 8;                            \
      _Pragma("unroll")                                                       \
      for (int mf_ = 0; mf_ < 4; ++mf_)                                       \
        af[ks_][mf_] = *(const bf16x8*)(ab_ + (mf_ * 16 + l16) * 64 + cx_);   \
    }                                                                         \
  } while (0)

#define LOAD_B(BUF_, QB_, DST_) do {                                          \
    const unsigned short* bb_ = Bs + (BUF_) * 16384 + ((QB_) * 128 + wn32) * 64; \
    _Pragma("unroll")                                                         \
    for (int ks_ = 0; ks_ < 2; ++ks_) {                                       \
      const int cx_ = ((ks_ * 4 + quad) ^ s7) * 8;                            \
      _Pragma("unroll")                                                       \
      for (int nf_ = 0; nf_ < 2; ++nf_)                                       \
        DST_[ks_][nf_] = *(const bf16x8*)(bb_ + (nf_ * 16 + l16) * 64 + cx_); \
    }                                                                         \
  } while (0)

#define MFMA_Q(QA_, QB_, BF_)                                                 \
    _Pragma("unroll")                                                         \
    for (int ks_ = 0; ks_ < 2; ++ks_)                                         \
      _Pragma("unroll")                                                       \
      for (int mf_ = 0; mf_ < 4; ++mf_)                                       \
        _Pragma("unroll")                                                     \
        for (int nf_ = 0; nf_ < 2; ++nf_)                                     \
          acc[QA_][QB_][mf_][nf_] = __builtin_amdgcn_mfma_f32_16x16x32_bf16(  \
              af[ks_][mf_], BF_[ks_][nf_], acc[QA_][QB_][mf_][nf_], 0, 0, 0)

#define WRITE_CQ(QA_, QB_) do {                                               \
    _Pragma("unroll")                                                         \
    for (int mf_ = 0; mf_ < 4; ++mf_)                                         \
      _Pragma("unroll")                                                       \
      for (int nf_ = 0; nf_ < 2; ++nf_) {                                     \
        const int row0_ = rowA0 + (QA_) * 128 + wm64 + mf_ * 16 + quad * 4;   \
        float* cp_ = C + (size_t)row0_ * COUT                                 \
                       + rowB0 + (QB_) * 128 + wn32 + nf_ * 16 + l16;         \
        _Pragma("unroll")                                                     \
        for (int r_ = 0; r_ < 4; ++r_)                                        \
            cp_[(size_t)r_ * COUT] = acc[QA_][QB_][mf_][nf_][r_];             \
      }                                                                       \
  } while (0)

// v4: raw barrier + setprio only; no lgkm drain, no sched pin. Compiler
// inserts fine-grained lgkmcnt(N) per MFMA operand dependency.
#define SYNC_PRE() do {                                                       \
    __builtin_amdgcn_s_barrier();                                             \
    __builtin_amdgcn_s_setprio(1);                                            \
  } while (0)

#define SYNC_POST() __builtin_amdgcn_s_setprio(0)

__global__ __launch_bounds__(512, 2) void gemm_8ph_v4(
    const unsigned short* __restrict__ A,   // [M, K] bf16
    const unsigned short* __restrict__ B,   // [N, K] bf16
    float* __restrict__ C,                  // [M, N] fp32
    int M) {
    (void)M;
    constexpr int K = CIN;

    __shared__ __align__(16) unsigned short As[2 * 16384];  // 2 x [256][64]
    __shared__ __align__(16) unsigned short Bs[2 * 16384];

    const int tid  = threadIdx.x;
    const int lane = tid & 63;
    const int w    = tid >> 6;
    const int quad = lane >> 4;
    const int l16  = lane & 15;
    const int s7   = l16 & 7;
    const int wm64 = (w >> 2) * 64;
    const int wn32 = (w & 3) * 32;

    const int rowA0 = blockIdx.x * 256;
    const int rowB0 = blockIdx.y * 256;

    const int stg_row = tid >> 3;
    const int c_data  = (tid & 7) ^ (stg_row & 7);
    const int tid8    = tid * 8;
    const unsigned short* pa = A + (size_t)(rowA0 + stg_row) * K + c_data * 8;
    const unsigned short* pb = B + (size_t)(rowB0 + stg_row) * K + c_data * 8;

    f32x4 acc[2][2][4][2] = {};

    // ---- prologue: tile0 -> buf0 (A0,B0,B1,A1), tile1 -> buf1 (A0,B0) ----
    STAGE_A(0, 0, 0); STAGE_B(0, 0, 0); STAGE_B(0, 1, 0); STAGE_A(0, 1, 0);
    STAGE_A(1, 0, 1); STAGE_B(1, 0, 1);
    asm volatile("s_waitcnt vmcnt(4)" ::: "memory");  // tile0 complete
    __builtin_amdgcn_s_barrier();

#pragma unroll 1
    for (int i = 0; i < 7; ++i) {          // steady-state: all stages unconditional
        const int k1 = 2 * i + 1;          // <= 13
        const int k2 = 2 * i + 2;          // <= 14
        const int k3 = 2 * i + 3;          // <= 15

        bf16x8 af[2][4];
        bf16x8 bf0[2][2], bf1[2][2];

        // even tile (buf0)
        LOAD_A(0, 0); LOAD_B(0, 0, bf0);
        STAGE_B(1, 1, k1);
        SYNC_PRE(); MFMA_Q(0, 0, bf0); SYNC_POST();
        __builtin_amdgcn_s_barrier();

        LOAD_B(0, 1, bf1);
        STAGE_A(1, 1, k1);
        SYNC_PRE(); MFMA_Q(0, 1, bf1); SYNC_POST();
        __builtin_amdgcn_s_barrier();

        LOAD_A(0, 1);
        STAGE_A(0, 0, k2);
        SYNC_PRE(); MFMA_Q(1, 0, bf0); SYNC_POST();
        __builtin_amdgcn_s_barrier();

        STAGE_B(0, 0, k2);
        SYNC_PRE(); MFMA_Q(1, 1, bf1); SYNC_POST();
        asm volatile("s_waitcnt vmcnt(4)" ::: "memory");   // K1: odd tile ready
        __builtin_amdgcn_s_barrier();

        // odd tile (buf1)
        LOAD_A(1, 0); LOAD_B(1, 0, bf0);
        STAGE_B(0, 1, k2);
        SYNC_PRE(); MFMA_Q(0, 0, bf0); SYNC_POST();
        __builtin_amdgcn_s_barrier();

        LOAD_B(1, 1, bf1);
        STAGE_A(0, 1, k2);
        SYNC_PRE(); MFMA_Q(0, 1, bf1); SYNC_POST();
        __builtin_amdgcn_s_barrier();

        LOAD_A(1, 1);
        STAGE_A(1, 0, k3);
        SYNC_PRE(); MFMA_Q(1, 0, bf0); SYNC_POST();
        __builtin_amdgcn_s_barrier();

        STAGE_B(1, 0, k3);
        SYNC_PRE(); MFMA_Q(1, 1, bf1); SYNC_POST();
        asm volatile("s_waitcnt vmcnt(4)" ::: "memory");   // K2: even tile ready
        __builtin_amdgcn_s_barrier();
    }

    // ---- peeled i=7: tiles 14 (buf0) and 15 (buf1) ----
    {
        bf16x8 af[2][4];
        bf16x8 bf0[2][2], bf1[2][2];

        // q1..q4: even tile (buf0); K1 = vmcnt(0) publishes buf1
        LOAD_A(0, 0); LOAD_B(0, 0, bf0);
        STAGE_B(1, 1, 15);
        SYNC_PRE(); MFMA_Q(0, 0, bf0); SYNC_POST();
        __builtin_amdgcn_s_barrier();

        LOAD_B(0, 1, bf1);
        STAGE_A(1, 1, 15);
        SYNC_PRE(); MFMA_Q(0, 1, bf1); SYNC_POST();
        __builtin_amdgcn_s_barrier();

        LOAD_A(0, 1);
        SYNC_PRE(); MFMA_Q(1, 0, bf0); SYNC_POST();
        __builtin_amdgcn_s_barrier();

        SYNC_PRE(); MFMA_Q(1, 1, bf1); SYNC_POST();
        asm volatile("s_waitcnt vmcnt(0)" ::: "memory");   // buf1 fully published
        __builtin_amdgcn_s_barrier();

        // q5..q8: odd tile (buf1), barrier-free; store each C-quadrant as it
        // finalizes so the 64MB tail drains under the remaining MFMA.
        LOAD_A(1, 0); LOAD_B(1, 0, bf0); LOAD_B(1, 1, bf1);
        __builtin_amdgcn_s_setprio(1); MFMA_Q(0, 0, bf0); __builtin_amdgcn_s_setprio(0);
        WRITE_CQ(0, 0);

        __builtin_amdgcn_s_setprio(1); MFMA_Q(0, 1, bf1); __builtin_amdgcn_s_setprio(0);
        WRITE_CQ(0, 1);

        LOAD_A(1, 1);
        __builtin_amdgcn_s_setprio(1); MFMA_Q(1, 0, bf0); __builtin_amdgcn_s_setprio(0);
        WRITE_CQ(1, 0);

        __builtin_amdgcn_s_setprio(1); MFMA_Q(1, 1, bf1); __builtin_amdgcn_s_setprio(0);
        WRITE_CQ(1, 1);
    }
}

extern "C" void kernel_launch(void* const* d_in, const int* in_sizes, int n_in,
                              void* d_out, int out_size, void* d_ws, size_t ws_size,
                              hipStream_t stream) {
    const float* x    = (const float*)d_in[0];   // [M, CIN] fp32
    const float* vals = (const float*)d_in[1];   // [nnz] fp32
    const int*   idx  = (const int*)d_in[2];     // [2, nnz] int32

    float* out = (float*)d_out;                  // [M, COUT] fp32

    const int nnz = in_sizes[2] / 2;
    const int M   = in_sizes[0] / CIN;

    const size_t wf_bytes = (size_t)COUT * CIN * sizeof(float);          // 4 MB
    const size_t wb_bytes = (size_t)COUT * CIN * sizeof(unsigned short); // 2 MB

    float*          Wf = (float*)d_ws;
    unsigned short* Wb = (unsigned short*)((char*)d_ws + wf_bytes);
    unsigned short* Xb = (unsigned short*)((char*)d_ws + wf_bytes + wb_bytes);

    const int nsb = (nnz + 255) / 256;                                    // 512
    const unsigned cvtx_blocks = (unsigned)((size_t)M * CIN / (256 * 8)); // 8192

    // 1) zero fp32 W (ws is poisoned 0xAA before every call)
    zero_f32<<<dim3(COUT * CIN / (256 * 4)), dim3(256), 0, stream>>>((float4*)Wf);
    // 2) scatter-add (needs zeroed W) || x -> bf16 (independent) in one launch
    scatter_cvtx<<<dim3((unsigned)nsb + cvtx_blocks), dim3(256), 0, stream>>>(
        vals, idx, idx + nnz, Wf, nnz, nsb, x, Xb);
    // 3) W -> bf16
    cvt_bf16_bulk<<<dim3(COUT * CIN / (256 * 8)), dim3(256), 0, stream>>>(Wf, Wb);
    // 4) GEMM with compiler-scheduled lgkm waits + peeled last iteration.
    gemm_8ph_v4<<<dim3(M / 256, COUT / 256), dim3(512), 0, stream>>>(Xb, Wb, out, M);
}